// Round 3
// baseline (288.161 us; speedup 1.0000x reference)
//
#include <hip/hip_runtime.h>

// TriplePairwiseCEFocalLoss: out = mean_b( cnt_b>0 ? sum_j(fl[b,j]*neg[b,j])/cnt_b : 0 )
//   neg[b,j] = (mask[b,j]==1) && j!=head[b] && j!=tail[b]
//   x  = scores[b,j] - scores[b,tail[b]]
//   e  = exp(x); sp = log(1+e) = softplus(x) = -logpt; pt = 1/(1+e)
//   fl = (1-clip(pt))^2 * sp
//
// R2 post-mortem: latency-bound (VGPR=28 -> compiler serialized loads).
// R3: explicit depth-4 software pipeline with rotating register buffers
// (fully unrolled -> static indices -> registers, not scratch). Head/tail
// exclusion hoisted out of the hot loop into a lane-0 correction.

__device__ __forceinline__ float focal_term(float x) {
    const float e  = __expf(x);              // x in ~[-12,12] for N(0,1) scores
    const float t  = 1.f + e;
    const float sp = __logf(t);              // softplus(x)
    float pt = __builtin_amdgcn_rcpf(t);     // exp(-sp)
    pt = fminf(fmaxf(pt, 1e-7f), 1.f - 1e-7f);
    const float om = 1.f - pt;
    return om * om * sp;
}

template <int S>
__global__ __launch_bounds__(256, 8) void focal_row_kernel(
    const float* __restrict__ scores,
    const int*   __restrict__ head_pos,
    const int*   __restrict__ tail_pos,
    const int*   __restrict__ mask,
    float*       __restrict__ row_out,
    int B)
{
    const int lane = threadIdx.x & 63;
    const int row  = blockIdx.x * 4 + (threadIdx.x >> 6);   // one wave per row
    if (row >= B) return;

    const int head = head_pos[row];
    const int tail = tail_pos[row];
    const float* srow = scores + (size_t)row * S;
    const int*   mrow = mask   + (size_t)row * S;
    const float4* s4 = reinterpret_cast<const float4*>(srow);
    const int4*   m4 = reinterpret_cast<const int4*>(mrow);
    const float pos = srow[tail];

    constexpr int NIT   = S / 4 / 64;   // float4 iterations per lane (16 @ S=4096)
    constexpr int DEPTH = 4;            // loads in flight: 2*DEPTH = 8
    static_assert(NIT >= DEPTH && NIT % 4 == 0, "shape");

    float4 sbuf[DEPTH];
    int4   mbuf[DEPTH];
    #pragma unroll
    for (int i = 0; i < DEPTH; ++i) {   // prologue: fill the pipeline
        sbuf[i] = s4[lane + 64 * i];
        mbuf[i] = m4[lane + 64 * i];
    }

    float fsum = 0.f;
    float cnt  = 0.f;

    #pragma unroll                      // FULL unroll -> all buf indices static
    for (int i = 0; i < NIT; ++i) {
        const float4 sv = sbuf[i & (DEPTH - 1)];
        const int4   mv = mbuf[i & (DEPTH - 1)];
        if (i + DEPTH < NIT) {          // steady-state prefetch, depth 4
            sbuf[i & (DEPTH - 1)] = s4[lane + 64 * (i + DEPTH)];
            mbuf[i & (DEPTH - 1)] = m4[lane + 64 * (i + DEPTH)];
        }
        const float se[4] = {sv.x, sv.y, sv.z, sv.w};
        const int   me[4] = {mv.x, mv.y, mv.z, mv.w};
        #pragma unroll
        for (int k = 0; k < 4; ++k) {
            const float fl = focal_term(se[k] - pos);
            const float on = (me[k] == 1) ? 1.f : 0.f;  // head/tail fixed up below
            fsum += fl * on;
            cnt  += on;
        }
    }

    // wave-level butterfly reduce (64 lanes)
    #pragma unroll
    for (int off = 32; off; off >>= 1) {
        fsum += __shfl_down(fsum, off, 64);
        cnt  += __shfl_down(cnt,  off, 64);
    }

    if (lane == 0) {
        // correction: remove head/tail elements that were counted as negatives.
        // (ref sets m[head]=-1 then m[tail]=-1; if head==tail only one element
        //  exists, so subtract each position once, guarding head==tail.)
        if (mrow[head] == 1) { fsum -= focal_term(srow[head] - pos); cnt -= 1.f; }
        if (tail != head && mrow[tail] == 1) { fsum -= focal_term(0.f); cnt -= 1.f; }
        row_out[row] = (cnt > 0.f) ? fsum / cnt : 0.f;
    }
}

// generic fallback (any S multiple of 4) — block-per-row, exact semantics
__global__ __launch_bounds__(256) void focal_row_generic(
    const float* __restrict__ scores,
    const int*   __restrict__ head_pos,
    const int*   __restrict__ tail_pos,
    const int*   __restrict__ mask,
    float*       __restrict__ row_out,
    int S)
{
    const int row  = blockIdx.x;
    const int tid  = threadIdx.x;
    const int head = head_pos[row];
    const int tail = tail_pos[row];
    const float* srow = scores + (size_t)row * S;
    const int*   mrow = mask   + (size_t)row * S;
    const float pos = srow[tail];
    float fsum = 0.f; float cnt = 0.f;
    for (int idx = tid; idx < S; idx += 256) {
        const float fl = focal_term(srow[idx] - pos);
        const bool isneg = (mrow[idx] == 1) && (idx != head) && (idx != tail);
        if (isneg) { fsum += fl; cnt += 1.f; }
    }
    #pragma unroll
    for (int off = 32; off; off >>= 1) {
        fsum += __shfl_down(fsum, off, 64);
        cnt  += __shfl_down(cnt,  off, 64);
    }
    __shared__ float sf[4]; __shared__ float sc[4];
    const int wave = tid >> 6;
    if ((tid & 63) == 0) { sf[wave] = fsum; sc[wave] = cnt; }
    __syncthreads();
    if (tid == 0) {
        float tot = sf[0] + sf[1] + sf[2] + sf[3];
        float c   = sc[0] + sc[1] + sc[2] + sc[3];
        row_out[row] = (c > 0.f) ? tot / c : 0.f;
    }
}

__global__ __launch_bounds__(256) void final_reduce_kernel(
    const float* __restrict__ row_out, float* __restrict__ out, int B)
{
    float sum = 0.f;
    const float4* r4 = reinterpret_cast<const float4*>(row_out);
    const int nvec = B >> 2;
    for (int i = threadIdx.x; i < nvec; i += 256) {
        float4 v = r4[i];
        sum += (v.x + v.y) + (v.z + v.w);
    }
    #pragma unroll
    for (int off = 32; off; off >>= 1) sum += __shfl_down(sum, off, 64);
    __shared__ float sf[4];
    const int wave = threadIdx.x >> 6;
    if ((threadIdx.x & 63) == 0) sf[wave] = sum;
    __syncthreads();
    if (threadIdx.x == 0) out[0] = (sf[0] + sf[1] + sf[2] + sf[3]) / (float)B;
}

extern "C" void kernel_launch(void* const* d_in, const int* in_sizes, int n_in,
                              void* d_out, int out_size, void* d_ws, size_t ws_size,
                              hipStream_t stream)
{
    const float* scores = (const float*)d_in[0];
    const int*   headp  = (const int*)d_in[1];
    const int*   tailp  = (const int*)d_in[2];
    const int*   maskp  = (const int*)d_in[3];
    const int B = in_sizes[1];
    const int S = in_sizes[0] / B;

    float* rowbuf = (float*)d_ws;   // B floats scratch, fully rewritten each call
    float* out    = (float*)d_out;

    if (S == 4096) {
        const int grid = (B + 3) / 4;   // one 64-lane wave per row
        focal_row_kernel<4096><<<grid, 256, 0, stream>>>(scores, headp, tailp, maskp, rowbuf, B);
    } else {
        focal_row_generic<<<B, 256, 0, stream>>>(scores, headp, tailp, maskp, rowbuf, S);
    }
    final_reduce_kernel<<<1, 256, 0, stream>>>(rowbuf, out, B);
}

// Round 4
// 283.703 us; speedup vs baseline: 1.0157x; 1.0157x over previous
//
#include <hip/hip_runtime.h>

// TriplePairwiseCEFocalLoss: out = mean_b( cnt_b>0 ? sum_j(fl[b,j]*neg[b,j])/cnt_b : 0 )
//   neg[b,j] = (mask[b,j]==1) && j!=head[b] && j!=tail[b]
//   x = scores[b,j]-scores[b,tail[b]]; e=exp(x); sp=log(1+e); pt=1/(1+e)
//   fl = (1-pt)^2 * sp    (clip of pt is inactive for |x|<=16 -> dropped)
//
// R3 post-mortem: compiler spilled the register pipeline to scratch
// (WRITE_SIZE 20.5 MB). R4: global_load_lds + counted vmcnt pipeline —
// loads have no dest VGPRs, asm waits pin the schedule. Wave-private
// 2-deep LDS double buffer (4 KB/wave, 16 KB/block, 8 blocks/CU).

#define GLL(gaddr, laddr)                                                          \
    __builtin_amdgcn_global_load_lds(                                              \
        (const __attribute__((address_space(1))) void*)(gaddr),                    \
        (__attribute__((address_space(3))) void*)(laddr), 16, 0, 0)

__device__ __forceinline__ float focal_term(float x) {
    const float e  = __expf(x);              // |x| <= ~11.2 for N(0,1) scores
    const float t  = 1.f + e;
    const float sp = __logf(t);              // softplus(x) = -logpt
    const float pt = __builtin_amdgcn_rcpf(t);
    const float om = 1.f - pt;
    return om * om * sp;
}

template <int S>
__global__ __launch_bounds__(256, 8) void focal_row_kernel(
    const float* __restrict__ scores,
    const int*   __restrict__ head_pos,
    const int*   __restrict__ tail_pos,
    const int*   __restrict__ mask,
    float*       __restrict__ row_out,
    int B)
{
    constexpr int NIT = S / 256;             // 16 stages of 256 elements
    static_assert(S % 256 == 0 && NIT >= 4, "shape");

    __shared__ float s_lds[4][2][256];       // [wave][stage][256 f32] = 8 KB
    __shared__ int   m_lds[4][2][256];       // 8 KB

    const int lane = threadIdx.x & 63;
    const int wid  = threadIdx.x >> 6;
    const int row  = blockIdx.x * 4 + wid;   // one wave per row (uniform guard)
    if (row >= B) return;

    const int head = head_pos[row];
    const int tail = tail_pos[row];
    const float* srow = scores + (size_t)row * S;
    const int*   mrow = mask   + (size_t)row * S;
    const float pos = srow[tail];

    // drain prologue loads so the pipeline's vmcnt counts are exact
    asm volatile("s_waitcnt vmcnt(0) lgkmcnt(0)" ::: "memory");

    // prologue: issue stages 0 and 1 (4 loads outstanding)
    GLL(srow + lane * 4,       &s_lds[wid][0][0]);
    GLL(mrow + lane * 4,       &m_lds[wid][0][0]);
    GLL(srow + 256 + lane * 4, &s_lds[wid][1][0]);
    GLL(mrow + 256 + lane * 4, &m_lds[wid][1][0]);

    float fsum = 0.f, cnt = 0.f;

    #pragma unroll                            // full unroll: compile-time i
    for (int i = 0; i < NIT; ++i) {
        if (i == NIT - 1) asm volatile("s_waitcnt vmcnt(0)" ::: "memory");
        else              asm volatile("s_waitcnt vmcnt(2)" ::: "memory");
        // stage i is in LDS; read own 16B (2-way bank alias only -> free)
        const float4 sv = reinterpret_cast<const float4*>(&s_lds[wid][i & 1][0])[lane];
        const int4   mv = reinterpret_cast<const int4*>(&m_lds[wid][i & 1][0])[lane];
        asm volatile("s_waitcnt lgkmcnt(0)" ::: "memory");   // reads complete...
        __builtin_amdgcn_sched_barrier(0);                   // ...and stay above
        if (i + 2 < NIT) {                    // refill this buffer with stage i+2
            GLL(srow + (i + 2) * 256 + lane * 4, &s_lds[wid][i & 1][0]);
            GLL(mrow + (i + 2) * 256 + lane * 4, &m_lds[wid][i & 1][0]);
        }
        const float se[4] = {sv.x, sv.y, sv.z, sv.w};
        const int   me[4] = {mv.x, mv.y, mv.z, mv.w};
        #pragma unroll
        for (int k = 0; k < 4; ++k) {
            const float fl = focal_term(se[k] - pos);
            const float on = (float)me[k];    // mask in {0,1}; head/tail fixed below
            fsum = fmaf(fl, on, fsum);
            cnt += on;
        }
    }

    // wave-level butterfly reduce (64 lanes)
    #pragma unroll
    for (int off = 32; off; off >>= 1) {
        fsum += __shfl_down(fsum, off, 64);
        cnt  += __shfl_down(cnt,  off, 64);
    }

    if (lane == 0) {
        // remove head/tail elements counted as negatives (ref: m[head]=-1, m[tail]=-1)
        if (mrow[head] == 1) { fsum -= focal_term(srow[head] - pos); cnt -= 1.f; }
        if (tail != head && mrow[tail] == 1) { fsum -= focal_term(0.f); cnt -= 1.f; }
        row_out[row] = (cnt > 0.f) ? fsum / cnt : 0.f;
    }
}

// generic fallback (any S multiple of 4) — block-per-row, exact semantics
__global__ __launch_bounds__(256) void focal_row_generic(
    const float* __restrict__ scores,
    const int*   __restrict__ head_pos,
    const int*   __restrict__ tail_pos,
    const int*   __restrict__ mask,
    float*       __restrict__ row_out,
    int S)
{
    const int row  = blockIdx.x;
    const int tid  = threadIdx.x;
    const int head = head_pos[row];
    const int tail = tail_pos[row];
    const float* srow = scores + (size_t)row * S;
    const int*   mrow = mask   + (size_t)row * S;
    const float pos = srow[tail];
    float fsum = 0.f, cnt = 0.f;
    for (int idx = tid; idx < S; idx += 256) {
        const float fl = focal_term(srow[idx] - pos);
        if ((mrow[idx] == 1) && (idx != head) && (idx != tail)) { fsum += fl; cnt += 1.f; }
    }
    #pragma unroll
    for (int off = 32; off; off >>= 1) {
        fsum += __shfl_down(fsum, off, 64);
        cnt  += __shfl_down(cnt,  off, 64);
    }
    __shared__ float sf[4]; __shared__ float sc[4];
    const int wave = tid >> 6;
    if ((tid & 63) == 0) { sf[wave] = fsum; sc[wave] = cnt; }
    __syncthreads();
    if (tid == 0) {
        float tot = sf[0] + sf[1] + sf[2] + sf[3];
        float c   = sc[0] + sc[1] + sc[2] + sc[3];
        row_out[row] = (c > 0.f) ? tot / c : 0.f;
    }
}

__global__ __launch_bounds__(256) void final_reduce_kernel(
    const float* __restrict__ row_out, float* __restrict__ out, int B)
{
    float sum = 0.f;
    const float4* r4 = reinterpret_cast<const float4*>(row_out);
    const int nvec = B >> 2;
    for (int i = threadIdx.x; i < nvec; i += 256) {
        float4 v = r4[i];
        sum += (v.x + v.y) + (v.z + v.w);
    }
    #pragma unroll
    for (int off = 32; off; off >>= 1) sum += __shfl_down(sum, off, 64);
    __shared__ float sf[4];
    const int wave = threadIdx.x >> 6;
    if ((threadIdx.x & 63) == 0) sf[wave] = sum;
    __syncthreads();
    if (threadIdx.x == 0) out[0] = (sf[0] + sf[1] + sf[2] + sf[3]) / (float)B;
}

extern "C" void kernel_launch(void* const* d_in, const int* in_sizes, int n_in,
                              void* d_out, int out_size, void* d_ws, size_t ws_size,
                              hipStream_t stream)
{
    const float* scores = (const float*)d_in[0];
    const int*   headp  = (const int*)d_in[1];
    const int*   tailp  = (const int*)d_in[2];
    const int*   maskp  = (const int*)d_in[3];
    const int B = in_sizes[1];
    const int S = in_sizes[0] / B;

    float* rowbuf = (float*)d_ws;   // B floats scratch, fully rewritten each call
    float* out    = (float*)d_out;

    if (S == 4096) {
        const int grid = (B + 3) / 4;   // one 64-lane wave per row
        focal_row_kernel<4096><<<grid, 256, 0, stream>>>(scores, headp, tailp, maskp, rowbuf, B);
    } else {
        focal_row_generic<<<B, 256, 0, stream>>>(scores, headp, tailp, maskp, rowbuf, S);
    }
    final_reduce_kernel<<<1, 256, 0, stream>>>(rowbuf, out, B);
}